// Round 1
// baseline (316.304 us; speedup 1.0000x reference)
//
#include <hip/hip_runtime.h>

// SAN Subtraction: x[8,64,56,56] fp32, K=7, stride=1, pad=3 (reflect), dil=1
// out[n,c,i*7+j, h*56+w] = x[n,c,h,w] - x[n,c, refl(h+i-3), refl(w+j-3)]
// out = [8,64,49,3136] fp32 = 314.7 MB  -> store-BW bound (floor ~55 us).
//
// Structure (R1): register-blocked over k. One thread owns (plane, 4-pixel
// chunk) and emits all 49 k outputs:
//   - center loaded ONCE (1x dwordx4) for 49 stores
//   - per row i: one aligned 12-float load (3x dwordx4), base clamped to
//     {0, w-4, 44} so loads are always in-bounds and 16B-aligned
//   - column reflection via compile-time-indexed register selects (2 cndmask
//     per virt element; border lanes are w==0 / w==52 only)
//   - row reflection folded into the row address (refl before load)
// VMEM per thread: 1 + 21 loads + 49 nt stores (vs 6 VMEM per 16B before).

#define HH 56
#define WW 56
#define KK 7
#define PP 3
#define KK2 49            // K*K
#define LL (HH * WW)      // 3136
#define LL4 (LL / 4)      // 784 float4 per (plane,k) slice
#define NPL 512           // N*C planes
#define NTHREADS (NPL * LL4)   // 401,408 = 1568 * 256 exactly

typedef float v4f __attribute__((ext_vector_type(4)));

__global__ __launch_bounds__(256) void san_sub_kernel(
        const float* __restrict__ x, float* __restrict__ out) {
    int tid = blockIdx.x * 256 + threadIdx.x;      // grid sized exactly: no bounds check

    int l4    = tid % LL4;
    int plane = tid / LL4;

    int h  = l4 / (WW / 4);        // 0..55
    int w4 = l4 - h * (WW / 4);    // 0..13
    int w  = w4 * 4;               // 0,4,...,52

    const float* xp = x + (long)plane * LL;

    // center: one aligned 16B load, reused for all 49 k
    v4f c = *reinterpret_cast<const v4f*>(xp + h * WW + w);

    bool isL = (w4 == 0);          // needs cols -3..-1 reflected
    bool isR = (w4 == 13);         // needs cols 56..58 reflected
    int base = isL ? 0 : (isR ? (WW - 12) : (w - 4));   // 16B-aligned, in-bounds

    v4f* o4 = reinterpret_cast<v4f*>(out) + ((long)plane * KK2 * LL4 + l4);

    #pragma unroll
    for (int i = 0; i < KK; ++i) {
        // row reflection (p=3 < 56: single bounce)
        int r = h + i - PP;
        r = (r < 0) ? -r : r;
        r = (r >= HH) ? (2 * HH - 2 - r) : r;

        const float* row = xp + r * WW + base;
        v4f a0 = *reinterpret_cast<const v4f*>(row);
        v4f a1 = *reinterpret_cast<const v4f*>(row + 4);
        v4f a2 = *reinterpret_cast<const v4f*>(row + 8);
        float rr[12] = {a0.x, a0.y, a0.z, a0.w,
                        a1.x, a1.y, a1.z, a1.w,
                        a2.x, a2.y, a2.z, a2.w};

        // virt[t] = x[plane][r][refl(w-3+t)], t = 0..9  (all reg indices
        // compile-time; border remap is 2 cndmask per element)
        float virt[10];
        #pragma unroll
        for (int t = 0; t < 10; ++t) {
            const int iInt = t + 1;                        // base = w-4: col w-3+t
            const int iLft = (t < 3) ? (3 - t) : (t - 3);  // base = 0:   col refl(t-3)
            const int iRgt = (t <= 6) ? (t + 5) : (17 - t);// base = 44:  col refl(49+t)
            virt[t] = isL ? rr[iLft] : (isR ? rr[iRgt] : rr[iInt]);
        }

        // 7 outputs for this row: window j..j+3 of virt
        #pragma unroll
        for (int j = 0; j < KK; ++j) {
            v4f rv;
            rv.x = c.x - virt[j + 0];
            rv.y = c.y - virt[j + 1];
            rv.z = c.z - virt[j + 2];
            rv.w = c.w - virt[j + 3];
            __builtin_nontemporal_store(rv, o4 + (i * KK + j) * LL4);
        }
    }
}

extern "C" void kernel_launch(void* const* d_in, const int* in_sizes, int n_in,
                              void* d_out, int out_size, void* d_ws, size_t ws_size,
                              hipStream_t stream) {
    const float* x = (const float*)d_in[0];
    float* out = (float*)d_out;
    int block = 256;
    int grid = NTHREADS / block;   // 1568 blocks, exact cover
    san_sub_kernel<<<grid, block, 0, stream>>>(x, out);
}

// Round 2
// 309.774 us; speedup vs baseline: 1.0211x; 1.0211x over previous
//
#include <hip/hip_runtime.h>

// SAN Subtraction: x[8,64,56,56] fp32, K=7, stride=1, pad=3 (reflect), dil=1
// out[n,c,i*7+j, h*56+w] = x[n,c,h,w] - x[n,c, refl(h+i-3), refl(w+j-3)]
// out = [8,64,49,3136] fp32 = 314.7 MB  -> store-BW floor ~50 us @ 6.3 TB/s.
//
// R2: split R1's per-thread k-block by kernel row. One thread per
// (plane, i, 4-pixel chunk): 2.81M threads (5.4x thread capacity, was 0.77x),
// 7 stores + 4 aligned dwordx4 loads each, small VGPR footprint.
// Theory: R1 was latency/occupancy-bound (only 401K deep-unroll threads),
// not VMEM-count bound. Keep load efficiency, restore TLP.

#define HH 56
#define WW 56
#define KK 7
#define PP 3
#define KK2 49            // K*K
#define LL (HH * WW)      // 3136
#define LL4 (LL / 4)      // 784 float4 per (plane,k) slice
#define NPL 512           // N*C planes
#define NTHREADS (NPL * KK * LL4)   // 2,809,856 = 10976 * 256 exactly

typedef float v4f __attribute__((ext_vector_type(4)));

__global__ __launch_bounds__(256) void san_sub_kernel(
        const float* __restrict__ x, float* __restrict__ out) {
    int tid = blockIdx.x * 256 + threadIdx.x;   // exact grid: no bounds check

    int l4    = tid % LL4;
    int rest  = tid / LL4;
    int i     = rest % KK;       // kernel row 0..6
    int plane = rest / KK;       // 0..511

    int h  = l4 / (WW / 4);      // 0..55
    int w4 = l4 - h * (WW / 4);  // 0..13
    int w  = w4 * 4;             // 0,4,...,52

    const float* xp = x + (long)plane * LL;

    // center: one aligned 16B load (L1/L2 hit; shared across the 7 i-threads)
    v4f c = *reinterpret_cast<const v4f*>(xp + h * WW + w);

    // row reflection (p=3 < 56: single bounce), folded into the load address
    int r = h + i - PP;
    r = (r < 0) ? -r : r;
    r = (r >= HH) ? (2 * HH - 2 - r) : r;

    bool isL = (w4 == 0);            // needs cols -3..-1 reflected
    bool isR = (w4 == 13);           // needs cols 56..58 reflected
    int base = isL ? 0 : (isR ? (WW - 12) : (w - 4));   // 16B-aligned, in-bounds

    const float* row = xp + r * WW + base;
    v4f a0 = *reinterpret_cast<const v4f*>(row);
    v4f a1 = *reinterpret_cast<const v4f*>(row + 4);
    v4f a2 = *reinterpret_cast<const v4f*>(row + 8);
    float rr[12] = {a0.x, a0.y, a0.z, a0.w,
                    a1.x, a1.y, a1.z, a1.w,
                    a2.x, a2.y, a2.z, a2.w};

    // virt[t] = x[plane][r][refl(w-3+t)], t = 0..9; compile-time reg indices,
    // border remap is 2 cndmask per element (only lanes w4==0 / w4==13 differ)
    float virt[10];
    #pragma unroll
    for (int t = 0; t < 10; ++t) {
        const int iInt = t + 1;                         // base = w-4: col w-3+t
        const int iLft = (t < 3) ? (3 - t) : (t - 3);   // base = 0:   col refl(t-3)
        const int iRgt = (t <= 6) ? (t + 5) : (17 - t); // base = 44:  col refl(49+t)
        virt[t] = isL ? rr[iLft] : (isR ? rr[iRgt] : rr[iInt]);
    }

    // 7 outputs for this kernel row: windows j..j+3 of virt
    v4f* o4 = reinterpret_cast<v4f*>(out) + ((long)plane * KK2 + i * KK) * LL4 + l4;
    #pragma unroll
    for (int j = 0; j < KK; ++j) {
        v4f rv;
        rv.x = c.x - virt[j + 0];
        rv.y = c.y - virt[j + 1];
        rv.z = c.z - virt[j + 2];
        rv.w = c.w - virt[j + 3];
        __builtin_nontemporal_store(rv, o4 + j * LL4);
    }
}

extern "C" void kernel_launch(void* const* d_in, const int* in_sizes, int n_in,
                              void* d_out, int out_size, void* d_ws, size_t ws_size,
                              hipStream_t stream) {
    const float* x = (const float*)d_in[0];
    float* out = (float*)d_out;
    int block = 256;
    int grid = NTHREADS / block;   // 10976 blocks, exact cover
    san_sub_kernel<<<grid, block, 0, stream>>>(x, out);
}